// Round 19
// baseline (1961.131 us; speedup 1.0000x reference)
//
#include <hip/hip_runtime.h>
#include <math.h>

// R18 post-mortem: gemv was L1-request-bound (9KB requests / 80 FMAs per
// wave-chunk; 4 waves duplicate the same W rows). gemvL: block = 16 UNIQUE
// W rows (4/wave), all NR act rows staged per 256-col chunk into
// double-buffered LDS via global_load_lds (17 insts/block/chunk instead of
// 20/wave); weights stream via registers (w0/w1 dbuf, 1 chunk ahead).
// Intensity 1.1 -> 4.2 flop/B-requested. acc[NR][4]=68 + w32 + transients
// ~= 125 VGPR @ launch_bounds(256,3) cap ~168 -> no spill, 3 blocks/CU,
// LDS 39KB/block. Cheap epilogue: 4-step shfl + 4-partial LDS reduce.
// k-split planes P[y][i][l]; consumers (attn/gelu/redln) sum planes.

__global__ void k0_init(const float* __restrict__ x,
                        const float* __restrict__ bias,
                        const float* __restrict__ cls,
                        float* __restrict__ ss,
                        float* __restrict__ altx) {
    int idx = blockIdx.x * 256 + threadIdx.x;
    if (idx < 17 * 2048) {
        int r = idx >> 11, m = idx & 2047;
        float v = bias[idx];
        if (r == 0) v += cls[m];
        ss[idx] = v;
    }
    if (idx < 16 * 2048) {
        int i = idx >> 11, m = idx & 2047;
        int c1 = m >> 6, c2 = m & 63;
        const float* p = x + (size_t)(c2 * 32 + c1) * 160 + i * 10;
        float s = 0.f;
#pragma unroll
        for (int j = 0; j < 10; ++j) s += p[j];
        altx[idx] = s * 0.1f;
    }
}

// grid (L/16, S); slab = CH*256; out[i,l] = sum_m act[i,m]*W[l,m]
template <int NR, int CH>
__global__ __launch_bounds__(256, 3) void gemvL(
    const float* __restrict__ W, const float* __restrict__ act,
    float* __restrict__ P, int L, int K) {
    __shared__ float abuf[2][NR][256];
    __shared__ float part[4][NR * 4][4];
    const int tid = threadIdx.x;
    const int lane = tid & 63;
    const int wv = tid >> 6;
    const int l0 = blockIdx.x * 16 + wv * 4;   // 4 UNIQUE rows per wave
    const int k0 = blockIdx.y * (CH * 256);
    const float* Wp = W + (size_t)l0 * K + k0 + lane * 4;

#define STAGE(c, buf)                                                          \
    for (int i_ = wv; i_ < NR; i_ += 4)                                        \
        __builtin_amdgcn_global_load_lds(                                      \
            (const __attribute__((address_space(1))) unsigned int*)            \
                (act + (size_t)i_ * K + k0 + (c) * 256 + lane * 4),            \
            (__attribute__((address_space(3))) unsigned int*)                  \
                (&abuf[buf][i_][0]), 16, 0, 0);

    STAGE(0, 0);

    float4 w0[4], w1[4];
#pragma unroll
    for (int r = 0; r < 4; ++r)
        w0[r] = *reinterpret_cast<const float4*>(Wp + (size_t)r * K);
    if (CH > 1) {
#pragma unroll
        for (int r = 0; r < 4; ++r)
            w1[r] = *reinterpret_cast<const float4*>(Wp + (size_t)r * K + 256);
    }

    float acc[NR][4];
#pragma unroll
    for (int i = 0; i < NR; ++i)
#pragma unroll
        for (int r = 0; r < 4; ++r) acc[i][r] = 0.f;

    __syncthreads();  // stage(0) landed everywhere

#pragma unroll
    for (int c = 0; c < CH; ++c) {
        if (c + 1 < CH) STAGE(c + 1, (c + 1) & 1);   // in flight over compute
#pragma unroll
        for (int i = 0; i < NR; ++i) {
            const float4 a4 =
                *reinterpret_cast<const float4*>(&abuf[c & 1][i][lane * 4]);
            acc[i][0] += a4.x * w0[0].x + a4.y * w0[0].y + a4.z * w0[0].z + a4.w * w0[0].w;
            acc[i][1] += a4.x * w0[1].x + a4.y * w0[1].y + a4.z * w0[1].z + a4.w * w0[1].w;
            acc[i][2] += a4.x * w0[2].x + a4.y * w0[2].y + a4.z * w0[2].z + a4.w * w0[2].w;
            acc[i][3] += a4.x * w0[3].x + a4.y * w0[3].y + a4.z * w0[3].z + a4.w * w0[3].w;
        }
#pragma unroll
        for (int r = 0; r < 4; ++r) w0[r] = w1[r];
        if (c + 2 < CH) {
#pragma unroll
            for (int r = 0; r < 4; ++r)
                w1[r] = *reinterpret_cast<const float4*>(
                    Wp + (size_t)r * K + (c + 2) * 256);
        }
        __syncthreads();  // stage(c+1) landed; abuf[c&1] reads done
    }
#undef STAGE

    // epilogue: 4-step shfl (reduce within 16-lane groups), 4 partials to LDS
#pragma unroll
    for (int i = 0; i < NR; ++i)
#pragma unroll
        for (int r = 0; r < 4; ++r) {
            float v = acc[i][r];
            v += __shfl_xor(v, 1);
            v += __shfl_xor(v, 2);
            v += __shfl_xor(v, 4);
            v += __shfl_xor(v, 8);
            const int o = i * 4 + r;
            if ((lane & 15) == (o & 15)) part[wv][o][lane >> 4] = v;
        }
    __syncthreads();
    for (int t = tid; t < NR * 16; t += 256) {
        const int w = t / (NR * 4), o = t % (NR * 4);
        const float s = part[w][o][0] + part[w][o][1] + part[w][o][2] + part[w][o][3];
        const int i = o >> 2, r = o & 3;
        P[(size_t)blockIdx.y * NR * L + (size_t)i * L +
          blockIdx.x * 16 + w * 4 + r] = s;
    }
}

// tbuf = gelu(sum_S Pf planes + fc1_b)
__global__ void red_gelu(const float* __restrict__ Pf, const float* __restrict__ fb,
                         float* __restrict__ out, int S, int NRL) {
    int idx = blockIdx.x * 256 + threadIdx.x;
    float s = fb[idx & 8191];
    for (int y = 0; y < S; ++y) s += Pf[(size_t)y * NRL + idx];
    out[idx] = 0.5f * s * (1.f + erff(s * 0.70710678f));
}

// one block per row: ss[row] += sum_S P[row] (+fb); lnout = LN(ss)*g+b
__global__ void redln(const float* __restrict__ P, int S, int rowoff, int NRL,
                      const float* __restrict__ fb, float* __restrict__ ss,
                      const float* __restrict__ g, const float* __restrict__ b,
                      float* __restrict__ lnout) {
    const int row = blockIdx.x;
    const int tid = threadIdx.x;
    const int base = row * 2048;
    float vv[8];
    float s = 0.f, q = 0.f;
#pragma unroll
    for (int c = 0; c < 8; ++c) {
        int col = tid + c * 256;
        float xv = ss[base + col];
        if (row >= rowoff) {
            const float* pp = P + (size_t)(row - rowoff) * 2048 + col;
            for (int y = 0; y < S; ++y) xv += pp[(size_t)y * NRL];
        }
        if (fb != nullptr) xv += fb[col];
        ss[base + col] = xv;
        vv[c] = xv;
        s += xv;
        q += xv * xv;
    }
#pragma unroll
    for (int off = 32; off; off >>= 1) {
        s += __shfl_xor(s, off);
        q += __shfl_xor(q, off);
    }
    __shared__ float red[8];
    int wvi = tid >> 6;
    if ((tid & 63) == 0) { red[wvi] = s; red[4 + wvi] = q; }
    __syncthreads();
    s = red[0] + red[1] + red[2] + red[3];
    q = red[4] + red[5] + red[6] + red[7];
    float mean = s * (1.f / 2048.f);
    float var = q * (1.f / 2048.f) - mean * mean;
    float rstd = rsqrtf(var + 1e-5f);
#pragma unroll
    for (int c = 0; c < 8; ++c) {
        int col = tid + c * 256;
        lnout[base + col] = (vv[c] - mean) * rstd * g[col] + b[col];
    }
}

// one block per head; sums S qkv k-planes inline (plane stride 104448)
__global__ void attn_kernel(const float* __restrict__ Pq, float* __restrict__ imv,
                            int S) {
    int h = blockIdx.x, lane = threadIdx.x;
    const float scale = 0.08838834764831845f;  // 1/sqrt(128)
    float run0 = 0.f, run1 = 0.f;
    for (int i = 0; i < 17; ++i) {
        const size_t idx = (size_t)i * 6144 + h * 128;
        float q0 = 0.f, q1 = 0.f, k0 = 0.f, k1 = 0.f, v0 = 0.f, v1 = 0.f;
        for (int s = 0; s < S; ++s) {
            const float* base = Pq + (size_t)s * 104448 + idx;
            q0 += base[lane];        q1 += base[lane + 64];
            k0 += base[2048 + lane]; k1 += base[2048 + lane + 64];
            v0 += base[4096 + lane]; v1 += base[4096 + lane + 64];
        }
        float p = q0 * k0 + q1 * k1;
#pragma unroll
        for (int off = 32; off; off >>= 1) p += __shfl_xor(p, off);
        float rsa = p * scale;
        float iv0 = rsa * v0, iv1 = rsa * v1;
        float o0, o1;
        if (i < 16) { run0 += iv0; run1 += iv1; o0 = run0; o1 = run1; }
        else        { o0 = iv0; o1 = iv1; }
        imv[(size_t)i * 2048 + h * 128 + lane] = o0;
        imv[(size_t)i * 2048 + h * 128 + lane + 64] = o1;
    }
}

extern "C" void kernel_launch(void* const* d_in, const int* in_sizes, int n_in,
                              void* d_out, int out_size, void* d_ws, size_t ws_size,
                              hipStream_t stream) {
    const float* x      = (const float*)d_in[0];
    const float* weight = (const float*)d_in[1];
    const float* bias   = (const float*)d_in[2];
    const float* cls    = (const float*)d_in[3];
    const float* Wqkv   = (const float*)d_in[4];
    const float* Wo     = (const float*)d_in[5];
    const float* ln1_g  = (const float*)d_in[6];
    const float* ln1_b  = (const float*)d_in[7];
    const float* ln2_g  = (const float*)d_in[8];
    const float* ln2_b  = (const float*)d_in[9];
    const float* ln3_g  = (const float*)d_in[10];
    const float* ln3_b  = (const float*)d_in[11];
    const float* fc1_w  = (const float*)d_in[12];
    const float* fc1_b  = (const float*)d_in[13];
    const float* fc2_w  = (const float*)d_in[14];
    const float* fc2_b  = (const float*)d_in[15];
    float* out = (float*)d_out;

    float* ws     = (float*)d_ws;
    float* ss     = ws;                  // 34816
    float* altx   = ws + 34816;          // 32768
    float* imv    = ws + 67584;          // 34816
    float* ln1buf = ws + 102400;         // 34816
    float* ln2buf = ws + 137216;         // 34816
    float* tbuf   = ws + 172032;         // 139264 (gelu out)
    float* Pq     = ws + 311296;         // 208896 (qkv 2 / weight 4 / Wo 4 planes)
    float* Pf     = ws + 520192;         // 278528 (fc1 2 planes / fc2 8 planes)

    k0_init<<<136, 256, 0, stream>>>(x, bias, cls, ss, altx);
    // ss[1:17] += altx @ weight.T  (4 planes [16][2048], CH=2)
    gemvL<16, 2><<<dim3(128, 4), 256, 0, stream>>>(weight, altx, Pq, 2048, 2048);
    redln<<<17, 256, 0, stream>>>(Pq, 4, 1, 32768, nullptr, ss, ln1_g, ln1_b, ln1buf);

    for (int k = 0; k < 4; ++k) {
        // qkv = Wqkv[k] @ ln1buf  (2 planes [17][6144], CH=4)
        gemvL<17, 4><<<dim3(384, 2), 256, 0, stream>>>(
            Wqkv + (size_t)k * 12582912, ln1buf, Pq, 6144, 2048);
        attn_kernel<<<16, 64, 0, stream>>>(Pq, imv, 2);
        // Wo  (4 planes [17][2048], CH=2)
        gemvL<17, 2><<<dim3(128, 4), 256, 0, stream>>>(
            Wo + (size_t)k * 4194304, imv, Pq, 2048, 2048);
        redln<<<17, 256, 0, stream>>>(Pq, 4, 0, 34816, nullptr, ss, ln2_g, ln2_b, ln2buf);
        // fc1 raw  (2 planes [17][8192], CH=4)
        gemvL<17, 4><<<dim3(512, 2), 256, 0, stream>>>(fc1_w, ln2buf, Pf, 8192, 2048);
        red_gelu<<<544, 256, 0, stream>>>(Pf, fc1_b, tbuf, 2, 139264);
        // fc2  (8 planes [17][2048], K=8192, CH=4)
        gemvL<17, 4><<<dim3(128, 8), 256, 0, stream>>>(fc2_w, tbuf, Pf, 2048, 8192);
        if (k < 3)
            redln<<<17, 256, 0, stream>>>(Pf, 8, 0, 34816, fc2_b, ss, ln1_g, ln1_b, ln1buf);
        else
            redln<<<17, 256, 0, stream>>>(Pf, 8, 0, 34816, fc2_b, ss, ln3_g, ln3_b, out);
    }
}

// Round 20
// 1068.122 us; speedup vs baseline: 1.8361x; 1.8361x over previous
//
#include <hip/hip_runtime.h>
#include <math.h>

// R19 spilled (VGPR=84 vs ~125 body). gemvS: same dedup idea, body sized to
// ~66 VGPR: block = 512 thr = 8 waves, wave owns 2 UNIQUE W rows (16/block),
// all NR act rows staged per 256-col chunk into double-buffered LDS via
// global_load_lds (34KB). acc[NR][2]=34 + w-dbuf 16 + transients ~= 66 regs
// -> fits any allocator pick >=84; launch_bounds(512,4) caps 128.
// Intensity 4.2 flop/B-requested (vs 1.1 in R16) -> L1 & VALU non-binding,
// HBM binds. Epilogue: 34 x 6-step shfl butterfly. k-split planes P[y][i][l];
// consumers (attn/gelu/redln) sum planes.

__global__ void k0_init(const float* __restrict__ x,
                        const float* __restrict__ bias,
                        const float* __restrict__ cls,
                        float* __restrict__ ss,
                        float* __restrict__ altx) {
    int idx = blockIdx.x * 256 + threadIdx.x;
    if (idx < 17 * 2048) {
        int r = idx >> 11, m = idx & 2047;
        float v = bias[idx];
        if (r == 0) v += cls[m];
        ss[idx] = v;
    }
    if (idx < 16 * 2048) {
        int i = idx >> 11, m = idx & 2047;
        int c1 = m >> 6, c2 = m & 63;
        const float* p = x + (size_t)(c2 * 32 + c1) * 160 + i * 10;
        float s = 0.f;
#pragma unroll
        for (int j = 0; j < 10; ++j) s += p[j];
        altx[idx] = s * 0.1f;
    }
}

// grid (L/16, S); slab = CH*256; out[i,l] = sum_m act[i,m]*W[l,m]
template <int NR, int CH>
__global__ __launch_bounds__(512, 4) void gemvS(
    const float* __restrict__ W, const float* __restrict__ act,
    float* __restrict__ P, int L, int K) {
    __shared__ float abuf[2][NR][256];
    const int tid = threadIdx.x;
    const int lane = tid & 63;
    const int wv = tid >> 6;                    // 0..7
    const int l0 = blockIdx.x * 16 + wv * 2;    // 2 UNIQUE rows per wave
    const int k0 = blockIdx.y * (CH * 256);
    const float* Wp = W + (size_t)l0 * K + k0 + lane * 4;

#define STAGE(c, buf)                                                          \
    for (int i_ = wv; i_ < NR; i_ += 8)                                        \
        __builtin_amdgcn_global_load_lds(                                      \
            (const __attribute__((address_space(1))) unsigned int*)            \
                (act + (size_t)i_ * K + k0 + (c) * 256 + lane * 4),            \
            (__attribute__((address_space(3))) unsigned int*)                  \
                (&abuf[buf][i_][0]), 16, 0, 0);

    STAGE(0, 0);

    float4 w0[2], w1[2];
#pragma unroll
    for (int r = 0; r < 2; ++r)
        w0[r] = *reinterpret_cast<const float4*>(Wp + (size_t)r * K);
    if (CH > 1) {
#pragma unroll
        for (int r = 0; r < 2; ++r)
            w1[r] = *reinterpret_cast<const float4*>(Wp + (size_t)r * K + 256);
    }

    float acc[NR][2];
#pragma unroll
    for (int i = 0; i < NR; ++i) { acc[i][0] = 0.f; acc[i][1] = 0.f; }

    __syncthreads();  // stage(0) landed (vmcnt drain at barrier)

#pragma unroll
    for (int c = 0; c < CH; ++c) {
        if (c + 1 < CH) STAGE(c + 1, (c + 1) & 1);  // in flight over compute
#pragma unroll
        for (int i = 0; i < NR; ++i) {
            const float4 a4 =
                *reinterpret_cast<const float4*>(&abuf[c & 1][i][lane * 4]);
            acc[i][0] += a4.x * w0[0].x + a4.y * w0[0].y + a4.z * w0[0].z + a4.w * w0[0].w;
            acc[i][1] += a4.x * w0[1].x + a4.y * w0[1].y + a4.z * w0[1].z + a4.w * w0[1].w;
        }
        // rotate THEN refill (R17 lesson: never clobber an unconsumed set)
#pragma unroll
        for (int r = 0; r < 2; ++r) w0[r] = w1[r];
        if (c + 2 < CH) {
#pragma unroll
            for (int r = 0; r < 2; ++r)
                w1[r] = *reinterpret_cast<const float4*>(
                    Wp + (size_t)r * K + (c + 2) * 256);
        }
        __syncthreads();  // stage(c+1) landed; abuf[c&1] reads complete
    }
#undef STAGE

    // epilogue: 64-lane butterfly per value; lane i*2+r keeps output (i, l0+r)
    float vout = 0.f;
#pragma unroll
    for (int i = 0; i < NR; ++i)
#pragma unroll
        for (int r = 0; r < 2; ++r) {
            float v = acc[i][r];
#pragma unroll
            for (int off = 32; off; off >>= 1) v += __shfl_xor(v, off);
            if (lane == i * 2 + r) vout = v;
        }
    if (lane < NR * 2)
        P[(size_t)blockIdx.y * NR * L + (size_t)(lane >> 1) * L +
          blockIdx.x * 16 + wv * 2 + (lane & 1)] = vout;
}

// tbuf = gelu(sum_S Pf planes + fc1_b)
__global__ void red_gelu(const float* __restrict__ Pf, const float* __restrict__ fb,
                         float* __restrict__ out, int S, int NRL) {
    int idx = blockIdx.x * 256 + threadIdx.x;
    float s = fb[idx & 8191];
    for (int y = 0; y < S; ++y) s += Pf[(size_t)y * NRL + idx];
    out[idx] = 0.5f * s * (1.f + erff(s * 0.70710678f));
}

// one block per row: ss[row] += sum_S P[row] (+fb); lnout = LN(ss)*g+b
__global__ void redln(const float* __restrict__ P, int S, int rowoff, int NRL,
                      const float* __restrict__ fb, float* __restrict__ ss,
                      const float* __restrict__ g, const float* __restrict__ b,
                      float* __restrict__ lnout) {
    const int row = blockIdx.x;
    const int tid = threadIdx.x;
    const int base = row * 2048;
    float vv[8];
    float s = 0.f, q = 0.f;
#pragma unroll
    for (int c = 0; c < 8; ++c) {
        int col = tid + c * 256;
        float xv = ss[base + col];
        if (row >= rowoff) {
            const float* pp = P + (size_t)(row - rowoff) * 2048 + col;
            for (int y = 0; y < S; ++y) xv += pp[(size_t)y * NRL];
        }
        if (fb != nullptr) xv += fb[col];
        ss[base + col] = xv;
        vv[c] = xv;
        s += xv;
        q += xv * xv;
    }
#pragma unroll
    for (int off = 32; off; off >>= 1) {
        s += __shfl_xor(s, off);
        q += __shfl_xor(q, off);
    }
    __shared__ float red[8];
    int wvi = tid >> 6;
    if ((tid & 63) == 0) { red[wvi] = s; red[4 + wvi] = q; }
    __syncthreads();
    s = red[0] + red[1] + red[2] + red[3];
    q = red[4] + red[5] + red[6] + red[7];
    float mean = s * (1.f / 2048.f);
    float var = q * (1.f / 2048.f) - mean * mean;
    float rstd = rsqrtf(var + 1e-5f);
#pragma unroll
    for (int c = 0; c < 8; ++c) {
        int col = tid + c * 256;
        lnout[base + col] = (vv[c] - mean) * rstd * g[col] + b[col];
    }
}

// one block per head; sums S qkv k-planes inline (plane stride 104448)
__global__ void attn_kernel(const float* __restrict__ Pq, float* __restrict__ imv,
                            int S) {
    int h = blockIdx.x, lane = threadIdx.x;
    const float scale = 0.08838834764831845f;  // 1/sqrt(128)
    float run0 = 0.f, run1 = 0.f;
    for (int i = 0; i < 17; ++i) {
        const size_t idx = (size_t)i * 6144 + h * 128;
        float q0 = 0.f, q1 = 0.f, k0 = 0.f, k1 = 0.f, v0 = 0.f, v1 = 0.f;
        for (int s = 0; s < S; ++s) {
            const float* base = Pq + (size_t)s * 104448 + idx;
            q0 += base[lane];        q1 += base[lane + 64];
            k0 += base[2048 + lane]; k1 += base[2048 + lane + 64];
            v0 += base[4096 + lane]; v1 += base[4096 + lane + 64];
        }
        float p = q0 * k0 + q1 * k1;
#pragma unroll
        for (int off = 32; off; off >>= 1) p += __shfl_xor(p, off);
        float rsa = p * scale;
        float iv0 = rsa * v0, iv1 = rsa * v1;
        float o0, o1;
        if (i < 16) { run0 += iv0; run1 += iv1; o0 = run0; o1 = run1; }
        else        { o0 = iv0; o1 = iv1; }
        imv[(size_t)i * 2048 + h * 128 + lane] = o0;
        imv[(size_t)i * 2048 + h * 128 + lane + 64] = o1;
    }
}

extern "C" void kernel_launch(void* const* d_in, const int* in_sizes, int n_in,
                              void* d_out, int out_size, void* d_ws, size_t ws_size,
                              hipStream_t stream) {
    const float* x      = (const float*)d_in[0];
    const float* weight = (const float*)d_in[1];
    const float* bias   = (const float*)d_in[2];
    const float* cls    = (const float*)d_in[3];
    const float* Wqkv   = (const float*)d_in[4];
    const float* Wo     = (const float*)d_in[5];
    const float* ln1_g  = (const float*)d_in[6];
    const float* ln1_b  = (const float*)d_in[7];
    const float* ln2_g  = (const float*)d_in[8];
    const float* ln2_b  = (const float*)d_in[9];
    const float* ln3_g  = (const float*)d_in[10];
    const float* ln3_b  = (const float*)d_in[11];
    const float* fc1_w  = (const float*)d_in[12];
    const float* fc1_b  = (const float*)d_in[13];
    const float* fc2_w  = (const float*)d_in[14];
    const float* fc2_b  = (const float*)d_in[15];
    float* out = (float*)d_out;

    float* ws     = (float*)d_ws;
    float* ss     = ws;                  // 34816
    float* altx   = ws + 34816;          // 32768
    float* imv    = ws + 67584;          // 34816
    float* ln1buf = ws + 102400;         // 34816
    float* ln2buf = ws + 137216;         // 34816
    float* tbuf   = ws + 172032;         // 139264 (gelu out)
    float* Pq     = ws + 311296;         // 208896 (qkv 2 / weight 4 / Wo 4 planes)
    float* Pf     = ws + 520192;         // 278528 (fc1 2 planes / fc2 8 planes)

    k0_init<<<136, 256, 0, stream>>>(x, bias, cls, ss, altx);
    // ss[1:17] += altx @ weight.T  (4 planes [16][2048], CH=2)
    gemvS<16, 2><<<dim3(128, 4), 512, 0, stream>>>(weight, altx, Pq, 2048, 2048);
    redln<<<17, 256, 0, stream>>>(Pq, 4, 1, 32768, nullptr, ss, ln1_g, ln1_b, ln1buf);

    for (int k = 0; k < 4; ++k) {
        // qkv = Wqkv[k] @ ln1buf  (2 planes [17][6144], CH=4)
        gemvS<17, 4><<<dim3(384, 2), 512, 0, stream>>>(
            Wqkv + (size_t)k * 12582912, ln1buf, Pq, 6144, 2048);
        attn_kernel<<<16, 64, 0, stream>>>(Pq, imv, 2);
        // Wo  (4 planes [17][2048], CH=2)
        gemvS<17, 2><<<dim3(128, 4), 512, 0, stream>>>(
            Wo + (size_t)k * 4194304, imv, Pq, 2048, 2048);
        redln<<<17, 256, 0, stream>>>(Pq, 4, 0, 34816, nullptr, ss, ln2_g, ln2_b, ln2buf);
        // fc1 raw  (2 planes [17][8192], CH=4)
        gemvS<17, 4><<<dim3(512, 2), 512, 0, stream>>>(fc1_w, ln2buf, Pf, 8192, 2048);
        red_gelu<<<544, 256, 0, stream>>>(Pf, fc1_b, tbuf, 2, 139264);
        // fc2  (8 planes [17][2048], K=8192, CH=4)
        gemvS<17, 4><<<dim3(128, 8), 512, 0, stream>>>(fc2_w, tbuf, Pf, 2048, 8192);
        if (k < 3)
            redln<<<17, 256, 0, stream>>>(Pf, 8, 0, 34816, fc2_b, ss, ln1_g, ln1_b, ln1buf);
        else
            redln<<<17, 256, 0, stream>>>(Pf, 8, 0, 34816, fc2_b, ss, ln3_g, ln3_b, out);
    }
}

// Round 21
// 680.605 us; speedup vs baseline: 2.8815x; 1.5694x over previous
//
#include <hip/hip_runtime.h>
#include <math.h>

// R16 (473us champion) with doubled per-request accumulation. gemv8: block =
// 256 thr = 4 waves sharing 8 UNIQUE W rows (L1 serves the 4x duplicate row
// requests); wave qt covers act rows I0..I0+4 (I0 = min(4qt, NR-5), boundary
// rows duplicated, bitwise-identical double-writes). Single-set weight+act
// registers (no prefetch: R18 proved act prefetch null; TLP covers latency).
// Per chunk: 13 load insts / 160 FMAs = 2x FLOP-per-request vs R16.
// acc[5][8]=40 + w32 + a20 + addr ~= 115 <= 128 cap of launch_bounds(256,4)
// (R15/R16 proven regime; WRITE_SIZE = spill tripwire).
// S k-split planes P[y][i][l]; consumers (attn/gelu/redln) sum planes.

__global__ void k0_init(const float* __restrict__ x,
                        const float* __restrict__ bias,
                        const float* __restrict__ cls,
                        float* __restrict__ ss,
                        float* __restrict__ altx) {
    int idx = blockIdx.x * 256 + threadIdx.x;
    if (idx < 17 * 2048) {
        int r = idx >> 11, m = idx & 2047;
        float v = bias[idx];
        if (r == 0) v += cls[m];
        ss[idx] = v;
    }
    if (idx < 16 * 2048) {
        int i = idx >> 11, m = idx & 2047;
        int c1 = m >> 6, c2 = m & 63;
        const float* p = x + (size_t)(c2 * 32 + c1) * 160 + i * 10;
        float s = 0.f;
#pragma unroll
        for (int j = 0; j < 10; ++j) s += p[j];
        altx[idx] = s * 0.1f;
    }
}

// grid (L/8, S); slab = CH*256; out[i,l] = sum_m act[i,m]*W[l,m]
template <int NR, int CH>
__global__ __launch_bounds__(256, 4) void gemv8(
    const float* __restrict__ W, const float* __restrict__ act,
    float* __restrict__ P, int L, int K) {
    const int lane = threadIdx.x & 63;
    const int qt = threadIdx.x >> 6;
    const int I0 = (qt * 4 < NR - 5) ? qt * 4 : NR - 5;
    const int l0 = blockIdx.x * 8;
    const int k0 = blockIdx.y * (CH * 256);
    const float* Wp = W + (size_t)l0 * K + k0 + lane * 4;
    const float* Ap = act + (size_t)I0 * K + k0 + lane * 4;

    float acc[5][8];
#pragma unroll
    for (int j = 0; j < 5; ++j)
#pragma unroll
        for (int r = 0; r < 8; ++r) acc[j][r] = 0.f;

#pragma unroll
    for (int c = 0; c < CH; ++c) {
        float4 w4[8], a4[5];
#pragma unroll
        for (int r = 0; r < 8; ++r)
            w4[r] = *reinterpret_cast<const float4*>(Wp + (size_t)r * K + c * 256);
#pragma unroll
        for (int j = 0; j < 5; ++j)
            a4[j] = *reinterpret_cast<const float4*>(Ap + (size_t)j * K + c * 256);
#pragma unroll
        for (int j = 0; j < 5; ++j)
#pragma unroll
            for (int r = 0; r < 8; ++r)
                acc[j][r] += a4[j].x * w4[r].x + a4[j].y * w4[r].y +
                             a4[j].z * w4[r].z + a4[j].w * w4[r].w;
    }

    // butterfly k-reduce; lane j*8+r keeps output (I0+j, l0+r)
    float vout = 0.f;
#pragma unroll
    for (int j = 0; j < 5; ++j)
#pragma unroll
        for (int r = 0; r < 8; ++r) {
            float v = acc[j][r];
#pragma unroll
            for (int off = 32; off; off >>= 1) v += __shfl_xor(v, off);
            if (lane == j * 8 + r) vout = v;
        }
    if (lane < 40)
        P[(size_t)blockIdx.y * NR * L + (size_t)(I0 + (lane >> 3)) * L +
          l0 + (lane & 7)] = vout;
}

// tbuf = gelu(sum_S Pf planes + fc1_b)
__global__ void red_gelu(const float* __restrict__ Pf, const float* __restrict__ fb,
                         float* __restrict__ out, int S, int NRL) {
    int idx = blockIdx.x * 256 + threadIdx.x;
    float s = fb[idx & 8191];
    for (int y = 0; y < S; ++y) s += Pf[(size_t)y * NRL + idx];
    out[idx] = 0.5f * s * (1.f + erff(s * 0.70710678f));
}

// one block per row: ss[row] += sum_S P[row] (+fb); lnout = LN(ss)*g+b
__global__ void redln(const float* __restrict__ P, int S, int rowoff, int NRL,
                      const float* __restrict__ fb, float* __restrict__ ss,
                      const float* __restrict__ g, const float* __restrict__ b,
                      float* __restrict__ lnout) {
    const int row = blockIdx.x;
    const int tid = threadIdx.x;
    const int base = row * 2048;
    float vv[8];
    float s = 0.f, q = 0.f;
#pragma unroll
    for (int c = 0; c < 8; ++c) {
        int col = tid + c * 256;
        float xv = ss[base + col];
        if (row >= rowoff) {
            const float* pp = P + (size_t)(row - rowoff) * 2048 + col;
            for (int y = 0; y < S; ++y) xv += pp[(size_t)y * NRL];
        }
        if (fb != nullptr) xv += fb[col];
        ss[base + col] = xv;
        vv[c] = xv;
        s += xv;
        q += xv * xv;
    }
#pragma unroll
    for (int off = 32; off; off >>= 1) {
        s += __shfl_xor(s, off);
        q += __shfl_xor(q, off);
    }
    __shared__ float red[8];
    int wvi = tid >> 6;
    if ((tid & 63) == 0) { red[wvi] = s; red[4 + wvi] = q; }
    __syncthreads();
    s = red[0] + red[1] + red[2] + red[3];
    q = red[4] + red[5] + red[6] + red[7];
    float mean = s * (1.f / 2048.f);
    float var = q * (1.f / 2048.f) - mean * mean;
    float rstd = rsqrtf(var + 1e-5f);
#pragma unroll
    for (int c = 0; c < 8; ++c) {
        int col = tid + c * 256;
        lnout[base + col] = (vv[c] - mean) * rstd * g[col] + b[col];
    }
}

// one block per head; sums S qkv k-planes inline (plane stride 104448)
__global__ void attn_kernel(const float* __restrict__ Pq, float* __restrict__ imv,
                            int S) {
    int h = blockIdx.x, lane = threadIdx.x;
    const float scale = 0.08838834764831845f;  // 1/sqrt(128)
    float run0 = 0.f, run1 = 0.f;
    for (int i = 0; i < 17; ++i) {
        const size_t idx = (size_t)i * 6144 + h * 128;
        float q0 = 0.f, q1 = 0.f, k0 = 0.f, k1 = 0.f, v0 = 0.f, v1 = 0.f;
        for (int s = 0; s < S; ++s) {
            const float* base = Pq + (size_t)s * 104448 + idx;
            q0 += base[lane];        q1 += base[lane + 64];
            k0 += base[2048 + lane]; k1 += base[2048 + lane + 64];
            v0 += base[4096 + lane]; v1 += base[4096 + lane + 64];
        }
        float p = q0 * k0 + q1 * k1;
#pragma unroll
        for (int off = 32; off; off >>= 1) p += __shfl_xor(p, off);
        float rsa = p * scale;
        float iv0 = rsa * v0, iv1 = rsa * v1;
        float o0, o1;
        if (i < 16) { run0 += iv0; run1 += iv1; o0 = run0; o1 = run1; }
        else        { o0 = iv0; o1 = iv1; }
        imv[(size_t)i * 2048 + h * 128 + lane] = o0;
        imv[(size_t)i * 2048 + h * 128 + lane + 64] = o1;
    }
}

extern "C" void kernel_launch(void* const* d_in, const int* in_sizes, int n_in,
                              void* d_out, int out_size, void* d_ws, size_t ws_size,
                              hipStream_t stream) {
    const float* x      = (const float*)d_in[0];
    const float* weight = (const float*)d_in[1];
    const float* bias   = (const float*)d_in[2];
    const float* cls    = (const float*)d_in[3];
    const float* Wqkv   = (const float*)d_in[4];
    const float* Wo     = (const float*)d_in[5];
    const float* ln1_g  = (const float*)d_in[6];
    const float* ln1_b  = (const float*)d_in[7];
    const float* ln2_g  = (const float*)d_in[8];
    const float* ln2_b  = (const float*)d_in[9];
    const float* ln3_g  = (const float*)d_in[10];
    const float* ln3_b  = (const float*)d_in[11];
    const float* fc1_w  = (const float*)d_in[12];
    const float* fc1_b  = (const float*)d_in[13];
    const float* fc2_w  = (const float*)d_in[14];
    const float* fc2_b  = (const float*)d_in[15];
    float* out = (float*)d_out;

    float* ws     = (float*)d_ws;
    float* ss     = ws;                  // 34816
    float* altx   = ws + 34816;          // 32768
    float* imv    = ws + 67584;          // 34816
    float* ln1buf = ws + 102400;         // 34816
    float* ln2buf = ws + 137216;         // 34816
    float* tbuf   = ws + 172032;         // 139264 (gelu out)
    float* Pq     = ws + 311296;         // 208896 (weight 4 / qkv 2 / Wo 4 planes)
    float* Pf     = ws + 520192;         // 278528 (fc1 2 planes / fc2 8 planes)

    k0_init<<<136, 256, 0, stream>>>(x, bias, cls, ss, altx);
    // ss[1:17] += altx @ weight.T  (4 planes [16][2048], CH=2)
    gemv8<16, 2><<<dim3(256, 4), 256, 0, stream>>>(weight, altx, Pq, 2048, 2048);
    redln<<<17, 256, 0, stream>>>(Pq, 4, 1, 32768, nullptr, ss, ln1_g, ln1_b, ln1buf);

    for (int k = 0; k < 4; ++k) {
        // qkv = Wqkv[k] @ ln1buf  (2 planes [17][6144], CH=4)
        gemv8<17, 4><<<dim3(768, 2), 256, 0, stream>>>(
            Wqkv + (size_t)k * 12582912, ln1buf, Pq, 6144, 2048);
        attn_kernel<<<16, 64, 0, stream>>>(Pq, imv, 2);
        // Wo  (4 planes [17][2048], CH=2)
        gemv8<17, 2><<<dim3(256, 4), 256, 0, stream>>>(
            Wo + (size_t)k * 4194304, imv, Pq, 2048, 2048);
        redln<<<17, 256, 0, stream>>>(Pq, 4, 0, 34816, nullptr, ss, ln2_g, ln2_b, ln2buf);
        // fc1 raw  (2 planes [17][8192], CH=4)
        gemv8<17, 4><<<dim3(1024, 2), 256, 0, stream>>>(fc1_w, ln2buf, Pf, 8192, 2048);
        red_gelu<<<544, 256, 0, stream>>>(Pf, fc1_b, tbuf, 2, 139264);
        // fc2  (8 planes [17][2048], K=8192, CH=4)
        gemv8<17, 4><<<dim3(256, 8), 256, 0, stream>>>(fc2_w, tbuf, Pf, 2048, 8192);
        if (k < 3)
            redln<<<17, 256, 0, stream>>>(Pf, 8, 0, 34816, fc2_b, ss, ln1_g, ln1_b, ln1buf);
        else
            redln<<<17, 256, 0, stream>>>(Pf, 8, 0, 34816, fc2_b, ss, ln3_g, ln3_b, out);
    }
}

// Round 22
// 485.615 us; speedup vs baseline: 4.0384x; 1.4015x over previous
//
#include <hip/hip_runtime.h>
#include <math.h>

// R16 (473us champion) with weight prefetch deepened 2 -> 3 chunks in flight
// (4-set ring w[c&3], compile-time indices via full unroll; refill slot AFTER
// consumption per R17 lesson). Depth evidence: depth0=680 (R21), depth1=503
// (R15), depth2=473 (R16); 4-wave/SIMD cover/chunk ~640cyc, HBM ~900cyc ->
// depth3 (~1900cyc cover) removes the weight stall. Live VGPR: w64 + acc20
// + a20 + addr ~= 114 <= 128 cap of launch_bounds(256,4) (R14-16 proven
// no-spill regime; WRITE_SIZE = spill tripwire). Acts single-set (R18: act
// prefetch null). Everything else byte-identical to R16.
// gemvP: block = 256 thr = 4 waves, owns 4 consecutive W rows; wave qt covers
// act rows I0..I0+4 (I0 = min(4qt, NR-5), boundary rows duplicated,
// bitwise-identical double-writes). S k-split planes P[y][i][l]; consumers
// (attn/gelu/redln) sum planes.

__global__ void k0_init(const float* __restrict__ x,
                        const float* __restrict__ bias,
                        const float* __restrict__ cls,
                        float* __restrict__ ss,
                        float* __restrict__ altx) {
    int idx = blockIdx.x * 256 + threadIdx.x;
    if (idx < 17 * 2048) {
        int r = idx >> 11, m = idx & 2047;
        float v = bias[idx];
        if (r == 0) v += cls[m];
        ss[idx] = v;
    }
    if (idx < 16 * 2048) {
        int i = idx >> 11, m = idx & 2047;
        int c1 = m >> 6, c2 = m & 63;
        const float* p = x + (size_t)(c2 * 32 + c1) * 160 + i * 10;
        float s = 0.f;
#pragma unroll
        for (int j = 0; j < 10; ++j) s += p[j];
        altx[idx] = s * 0.1f;
    }
}

// grid (L/4, S); slab = CH*256; out[i,l] = sum_m act[i,m]*W[l,m]
template <int NR, int CH>
__global__ __launch_bounds__(256, 4) void gemvP(
    const float* __restrict__ W, const float* __restrict__ act,
    float* __restrict__ P, int L, int K) {
    const int lane = threadIdx.x & 63;
    const int qt = threadIdx.x >> 6;
    const int I0 = (qt * 4 < NR - 5) ? qt * 4 : NR - 5;
    const int l0 = blockIdx.x * 4;
    const int k0 = blockIdx.y * (CH * 256);
    const float* Wp = W + (size_t)l0 * K + k0 + lane * 4;
    const float* Ap = act + (size_t)I0 * K + k0 + lane * 4;

    float acc[5][4];
#pragma unroll
    for (int j = 0; j < 5; ++j)
#pragma unroll
        for (int r = 0; r < 4; ++r) acc[j][r] = 0.f;

    // 4-slot weight ring: slots 0..3 hold chunks 0..3 initially
    float4 w[4][4];
#pragma unroll
    for (int s = 0; s < 4; ++s) {
        if (s < CH) {
#pragma unroll
            for (int r = 0; r < 4; ++r)
                w[s][r] = *reinterpret_cast<const float4*>(
                    Wp + (size_t)r * K + s * 256);
        }
    }

#pragma unroll
    for (int c = 0; c < CH; ++c) {
        // act loads for this chunk (single-set; R18: prefetch null)
        float4 a4[5];
#pragma unroll
        for (int j = 0; j < 5; ++j)
            a4[j] = *reinterpret_cast<const float4*>(Ap + (size_t)j * K + c * 256);
        // FMA with ring slot c&3 (loaded 4 chunks ago)
#pragma unroll
        for (int j = 0; j < 5; ++j)
#pragma unroll
            for (int r = 0; r < 4; ++r)
                acc[j][r] += a4[j].x * w[c & 3][r].x + a4[j].y * w[c & 3][r].y +
                             a4[j].z * w[c & 3][r].z + a4[j].w * w[c & 3][r].w;
        // refill the just-consumed slot with chunk c+4 (after consumption)
        if (c + 4 < CH) {
#pragma unroll
            for (int r = 0; r < 4; ++r)
                w[c & 3][r] = *reinterpret_cast<const float4*>(
                    Wp + (size_t)r * K + (c + 4) * 256);
        }
    }

    // butterfly k-reduce; lane j*4+r keeps output (I0+j, l0+r)
    float vout = 0.f;
#pragma unroll
    for (int j = 0; j < 5; ++j)
#pragma unroll
        for (int r = 0; r < 4; ++r) {
            float v = acc[j][r];
#pragma unroll
            for (int off = 32; off; off >>= 1) v += __shfl_xor(v, off);
            if (lane == j * 4 + r) vout = v;
        }
    if (lane < 20)
        P[(size_t)blockIdx.y * NR * L + (size_t)(I0 + (lane >> 2)) * L +
          l0 + (lane & 3)] = vout;
}

// tbuf = gelu(Pf + fc1_b)
__global__ void red_gelu(const float* __restrict__ Pf, const float* __restrict__ fb,
                         float* __restrict__ out) {
    int idx = blockIdx.x * 256 + threadIdx.x;
    float s = fb[idx & 8191] + Pf[idx];
    out[idx] = 0.5f * s * (1.f + erff(s * 0.70710678f));
}

// one block per row: ss[row] += sum_S P[row] (+fb); lnout = LN(ss)*g+b
__global__ void redln(const float* __restrict__ P, int S, int rowoff, int NRL,
                      const float* __restrict__ fb, float* __restrict__ ss,
                      const float* __restrict__ g, const float* __restrict__ b,
                      float* __restrict__ lnout) {
    const int row = blockIdx.x;
    const int tid = threadIdx.x;
    const int base = row * 2048;
    float vv[8];
    float s = 0.f, q = 0.f;
#pragma unroll
    for (int c = 0; c < 8; ++c) {
        int col = tid + c * 256;
        float xv = ss[base + col];
        if (row >= rowoff) {
            const float* pp = P + (size_t)(row - rowoff) * 2048 + col;
            for (int y = 0; y < S; ++y) xv += pp[(size_t)y * NRL];
        }
        if (fb != nullptr) xv += fb[col];
        ss[base + col] = xv;
        vv[c] = xv;
        s += xv;
        q += xv * xv;
    }
#pragma unroll
    for (int off = 32; off; off >>= 1) {
        s += __shfl_xor(s, off);
        q += __shfl_xor(q, off);
    }
    __shared__ float red[8];
    int wvi = tid >> 6;
    if ((tid & 63) == 0) { red[wvi] = s; red[4 + wvi] = q; }
    __syncthreads();
    s = red[0] + red[1] + red[2] + red[3];
    q = red[4] + red[5] + red[6] + red[7];
    float mean = s * (1.f / 2048.f);
    float var = q * (1.f / 2048.f) - mean * mean;
    float rstd = rsqrtf(var + 1e-5f);
#pragma unroll
    for (int c = 0; c < 8; ++c) {
        int col = tid + c * 256;
        lnout[base + col] = (vv[c] - mean) * rstd * g[col] + b[col];
    }
}

// one block per head; 64 threads; reads qkv directly
__global__ void attn_kernel(const float* __restrict__ qkv, float* __restrict__ imv) {
    int h = blockIdx.x, lane = threadIdx.x;
    const float scale = 0.08838834764831845f;  // 1/sqrt(128)
    float run0 = 0.f, run1 = 0.f;
    for (int i = 0; i < 17; ++i) {
        const float* base = qkv + (size_t)i * 6144 + h * 128;
        float q0 = base[lane], q1 = base[lane + 64];
        float k0 = base[2048 + lane], k1 = base[2048 + lane + 64];
        float v0 = base[4096 + lane], v1 = base[4096 + lane + 64];
        float p = q0 * k0 + q1 * k1;
#pragma unroll
        for (int off = 32; off; off >>= 1) p += __shfl_xor(p, off);
        float rsa = p * scale;
        float iv0 = rsa * v0, iv1 = rsa * v1;
        float o0, o1;
        if (i < 16) { run0 += iv0; run1 += iv1; o0 = run0; o1 = run1; }
        else        { o0 = iv0; o1 = iv1; }
        imv[(size_t)i * 2048 + h * 128 + lane] = o0;
        imv[(size_t)i * 2048 + h * 128 + lane + 64] = o1;
    }
}

extern "C" void kernel_launch(void* const* d_in, const int* in_sizes, int n_in,
                              void* d_out, int out_size, void* d_ws, size_t ws_size,
                              hipStream_t stream) {
    const float* x      = (const float*)d_in[0];
    const float* weight = (const float*)d_in[1];
    const float* bias   = (const float*)d_in[2];
    const float* cls    = (const float*)d_in[3];
    const float* Wqkv   = (const float*)d_in[4];
    const float* Wo     = (const float*)d_in[5];
    const float* ln1_g  = (const float*)d_in[6];
    const float* ln1_b  = (const float*)d_in[7];
    const float* ln2_g  = (const float*)d_in[8];
    const float* ln2_b  = (const float*)d_in[9];
    const float* ln3_g  = (const float*)d_in[10];
    const float* ln3_b  = (const float*)d_in[11];
    const float* fc1_w  = (const float*)d_in[12];
    const float* fc1_b  = (const float*)d_in[13];
    const float* fc2_w  = (const float*)d_in[14];
    const float* fc2_b  = (const float*)d_in[15];
    float* out = (float*)d_out;

    float* ws     = (float*)d_ws;
    float* ss     = ws;                  // 34816
    float* altx   = ws + 34816;          // 32768
    float* imv    = ws + 67584;          // 34816
    float* qkv    = ws + 102400;         // 104448
    float* Pf     = ws + 206848;         // 139264 (fc1 raw)
    float* tbuf   = ws + 346112;         // 139264 (gelu out)
    float* ln1buf = ws + 485376;         // 34816
    float* ln2buf = ws + 520192;         // 34816
    float* Pg     = ws + 555008;         // 139264 (k-split planes)

    k0_init<<<136, 256, 0, stream>>>(x, bias, cls, ss, altx);
    // ss[1:17] += altx @ weight.T  (2 planes [16][2048], CH=4)
    gemvP<16, 4><<<dim3(512, 2), 256, 0, stream>>>(weight, altx, Pg, 2048, 2048);
    redln<<<17, 256, 0, stream>>>(Pg, 2, 1, 32768, nullptr, ss, ln1_g, ln1_b, ln1buf);

    for (int k = 0; k < 4; ++k) {
        // qkv = Wqkv[k] @ ln1buf  (direct, L=6144, CH=8)
        gemvP<17, 8><<<dim3(1536, 1), 256, 0, stream>>>(
            Wqkv + (size_t)k * 12582912, ln1buf, qkv, 6144, 2048);
        attn_kernel<<<16, 64, 0, stream>>>(qkv, imv);
        // Pg = imv @ Wo[k].T  (2 planes [17][2048], CH=4)
        gemvP<17, 4><<<dim3(512, 2), 256, 0, stream>>>(
            Wo + (size_t)k * 4194304, imv, Pg, 2048, 2048);
        redln<<<17, 256, 0, stream>>>(Pg, 2, 0, 34816, nullptr, ss, ln2_g, ln2_b, ln2buf);
        // Pf = fc1_w @ ln2buf  (direct raw, L=8192, CH=8)
        gemvP<17, 8><<<dim3(2048, 1), 256, 0, stream>>>(fc1_w, ln2buf, Pf, 8192, 2048);
        red_gelu<<<544, 256, 0, stream>>>(Pf, fc1_b, tbuf);
        // Pg = fc2_w @ tbuf  (4 planes [17][2048], K=8192, CH=8)
        gemvP<17, 8><<<dim3(512, 4), 256, 0, stream>>>(fc2_w, tbuf, Pg, 2048, 8192);
        if (k < 3)
            redln<<<17, 256, 0, stream>>>(Pg, 4, 0, 34816, fc2_b, ss, ln1_g, ln1_b, ln1buf);
        else
            redln<<<17, 256, 0, stream>>>(Pg, 4, 0, 34816, fc2_b, ss, ln3_g, ln3_b, out);
    }
}

// Round 24
// 485.053 us; speedup vs baseline: 4.0431x; 1.0012x over previous
//
#include <hip/hip_runtime.h>
#include <math.h>

// R16 (473us champion, depth-2 weight ring) + NON-TEMPORAL loads for the
// never-re-read weights (Wqkv[k]/Wo[k]/weight read exactly once per launch;
// streaming them through L2 evicts the act slabs -> act loads miss to L3/HBM).
// fc1/fc2 re-read 4x stay temporal. R23 compile fix: nontemporal builtin
// needs a NATIVE clang vector type, not HIP_vector_type -> use
// ext_vector_type(4) float and bit-cast. fc2 slab 4096 (CH=16, 2 planes).
// gemvP<NR,CH,NT>: block = 256 thr = 4 waves, owns 4 consecutive W rows;
// wave qt covers act rows I0..I0+4 (I0 = min(4qt, NR-5), boundary rows
// duplicated, bitwise-identical double-writes). Weights 2 chunks in flight
// (w0/w1/w2, rotate-then-refill per R17). Live VGPR ~118 <= 128 cap of
// launch_bounds(256,4) (R14-16 proven no-spill; WRITE_SIZE = tripwire).
// S k-split planes P[y][i][l]; consumers (attn/gelu/redln) sum planes.

typedef float vfloat4 __attribute__((ext_vector_type(4)));

__global__ void k0_init(const float* __restrict__ x,
                        const float* __restrict__ bias,
                        const float* __restrict__ cls,
                        float* __restrict__ ss,
                        float* __restrict__ altx) {
    int idx = blockIdx.x * 256 + threadIdx.x;
    if (idx < 17 * 2048) {
        int r = idx >> 11, m = idx & 2047;
        float v = bias[idx];
        if (r == 0) v += cls[m];
        ss[idx] = v;
    }
    if (idx < 16 * 2048) {
        int i = idx >> 11, m = idx & 2047;
        int c1 = m >> 6, c2 = m & 63;
        const float* p = x + (size_t)(c2 * 32 + c1) * 160 + i * 10;
        float s = 0.f;
#pragma unroll
        for (int j = 0; j < 10; ++j) s += p[j];
        altx[idx] = s * 0.1f;
    }
}

// grid (L/4, S); slab = CH*256; out[i,l] = sum_m act[i,m]*W[l,m]
template <int NR, int CH, bool NT>
__global__ __launch_bounds__(256, 4) void gemvP(
    const float* __restrict__ W, const float* __restrict__ act,
    float* __restrict__ P, int L, int K) {
    const int lane = threadIdx.x & 63;
    const int qt = threadIdx.x >> 6;
    const int I0 = (qt * 4 < NR - 5) ? qt * 4 : NR - 5;
    const int l0 = blockIdx.x * 4;
    const int k0 = blockIdx.y * (CH * 256);
    const float* Wp = W + (size_t)l0 * K + k0 + lane * 4;
    const float* Ap = act + (size_t)I0 * K + k0 + lane * 4;

    auto LDW = [](const float* p) -> vfloat4 {
        if (NT) return __builtin_nontemporal_load(
                    reinterpret_cast<const vfloat4*>(p));
        return *reinterpret_cast<const vfloat4*>(p);
    };

    float acc[5][4];
#pragma unroll
    for (int j = 0; j < 5; ++j)
#pragma unroll
        for (int r = 0; r < 4; ++r) acc[j][r] = 0.f;

    vfloat4 w0[4], w1[4], w2[4], a4[5];
#pragma unroll
    for (int r = 0; r < 4; ++r) w0[r] = LDW(Wp + (size_t)r * K);
    if (CH > 1) {
#pragma unroll
        for (int r = 0; r < 4; ++r) w1[r] = LDW(Wp + (size_t)r * K + 256);
    }
    if (CH > 2) {
#pragma unroll
        for (int r = 0; r < 4; ++r) w2[r] = LDW(Wp + (size_t)r * K + 512);
    }

#pragma unroll
    for (int c = 0; c < CH; ++c) {
        // act loads for this chunk (single-set; R18: act prefetch null)
#pragma unroll
        for (int j = 0; j < 5; ++j)
            a4[j] = *reinterpret_cast<const vfloat4*>(Ap + (size_t)j * K + c * 256);
        // FMA on current regs
#pragma unroll
        for (int j = 0; j < 5; ++j)
#pragma unroll
            for (int r = 0; r < 4; ++r)
                acc[j][r] += a4[j].x * w0[r].x + a4[j].y * w0[r].y +
                             a4[j].z * w0[r].z + a4[j].w * w0[r].w;
        // rotate THEN refill (R17 lesson: never clobber an unconsumed set)
#pragma unroll
        for (int r = 0; r < 4; ++r) w0[r] = w1[r];
#pragma unroll
        for (int r = 0; r < 4; ++r) w1[r] = w2[r];
        if (c + 3 < CH) {
#pragma unroll
            for (int r = 0; r < 4; ++r)
                w2[r] = LDW(Wp + (size_t)r * K + (c + 3) * 256);
        }
    }

    // butterfly k-reduce; lane j*4+r keeps output (I0+j, l0+r)
    float vout = 0.f;
#pragma unroll
    for (int j = 0; j < 5; ++j)
#pragma unroll
        for (int r = 0; r < 4; ++r) {
            float v = acc[j][r];
#pragma unroll
            for (int off = 32; off; off >>= 1) v += __shfl_xor(v, off);
            if (lane == j * 4 + r) vout = v;
        }
    if (lane < 20)
        P[(size_t)blockIdx.y * NR * L + (size_t)(I0 + (lane >> 2)) * L +
          l0 + (lane & 3)] = vout;
}

// tbuf = gelu(Pf + fc1_b)
__global__ void red_gelu(const float* __restrict__ Pf, const float* __restrict__ fb,
                         float* __restrict__ out) {
    int idx = blockIdx.x * 256 + threadIdx.x;
    float s = fb[idx & 8191] + Pf[idx];
    out[idx] = 0.5f * s * (1.f + erff(s * 0.70710678f));
}

// one block per row: ss[row] += sum_S P[row] (+fb); lnout = LN(ss)*g+b
__global__ void redln(const float* __restrict__ P, int S, int rowoff, int NRL,
                      const float* __restrict__ fb, float* __restrict__ ss,
                      const float* __restrict__ g, const float* __restrict__ b,
                      float* __restrict__ lnout) {
    const int row = blockIdx.x;
    const int tid = threadIdx.x;
    const int base = row * 2048;
    float vv[8];
    float s = 0.f, q = 0.f;
#pragma unroll
    for (int c = 0; c < 8; ++c) {
        int col = tid + c * 256;
        float xv = ss[base + col];
        if (row >= rowoff) {
            const float* pp = P + (size_t)(row - rowoff) * 2048 + col;
            for (int y = 0; y < S; ++y) xv += pp[(size_t)y * NRL];
        }
        if (fb != nullptr) xv += fb[col];
        ss[base + col] = xv;
        vv[c] = xv;
        s += xv;
        q += xv * xv;
    }
#pragma unroll
    for (int off = 32; off; off >>= 1) {
        s += __shfl_xor(s, off);
        q += __shfl_xor(q, off);
    }
    __shared__ float red[8];
    int wvi = tid >> 6;
    if ((tid & 63) == 0) { red[wvi] = s; red[4 + wvi] = q; }
    __syncthreads();
    s = red[0] + red[1] + red[2] + red[3];
    q = red[4] + red[5] + red[6] + red[7];
    float mean = s * (1.f / 2048.f);
    float var = q * (1.f / 2048.f) - mean * mean;
    float rstd = rsqrtf(var + 1e-5f);
#pragma unroll
    for (int c = 0; c < 8; ++c) {
        int col = tid + c * 256;
        lnout[base + col] = (vv[c] - mean) * rstd * g[col] + b[col];
    }
}

// one block per head; 64 threads; reads qkv directly
__global__ void attn_kernel(const float* __restrict__ qkv, float* __restrict__ imv) {
    int h = blockIdx.x, lane = threadIdx.x;
    const float scale = 0.08838834764831845f;  // 1/sqrt(128)
    float run0 = 0.f, run1 = 0.f;
    for (int i = 0; i < 17; ++i) {
        const float* base = qkv + (size_t)i * 6144 + h * 128;
        float q0 = base[lane], q1 = base[lane + 64];
        float k0 = base[2048 + lane], k1 = base[2048 + lane + 64];
        float v0 = base[4096 + lane], v1 = base[4096 + lane + 64];
        float p = q0 * k0 + q1 * k1;
#pragma unroll
        for (int off = 32; off; off >>= 1) p += __shfl_xor(p, off);
        float rsa = p * scale;
        float iv0 = rsa * v0, iv1 = rsa * v1;
        float o0, o1;
        if (i < 16) { run0 += iv0; run1 += iv1; o0 = run0; o1 = run1; }
        else        { o0 = iv0; o1 = iv1; }
        imv[(size_t)i * 2048 + h * 128 + lane] = o0;
        imv[(size_t)i * 2048 + h * 128 + lane + 64] = o1;
    }
}

extern "C" void kernel_launch(void* const* d_in, const int* in_sizes, int n_in,
                              void* d_out, int out_size, void* d_ws, size_t ws_size,
                              hipStream_t stream) {
    const float* x      = (const float*)d_in[0];
    const float* weight = (const float*)d_in[1];
    const float* bias   = (const float*)d_in[2];
    const float* cls    = (const float*)d_in[3];
    const float* Wqkv   = (const float*)d_in[4];
    const float* Wo     = (const float*)d_in[5];
    const float* ln1_g  = (const float*)d_in[6];
    const float* ln1_b  = (const float*)d_in[7];
    const float* ln2_g  = (const float*)d_in[8];
    const float* ln2_b  = (const float*)d_in[9];
    const float* ln3_g  = (const float*)d_in[10];
    const float* ln3_b  = (const float*)d_in[11];
    const float* fc1_w  = (const float*)d_in[12];
    const float* fc1_b  = (const float*)d_in[13];
    const float* fc2_w  = (const float*)d_in[14];
    const float* fc2_b  = (const float*)d_in[15];
    float* out = (float*)d_out;

    float* ws     = (float*)d_ws;
    float* ss     = ws;                  // 34816
    float* altx   = ws + 34816;          // 32768
    float* imv    = ws + 67584;          // 34816
    float* qkv    = ws + 102400;         // 104448
    float* Pf     = ws + 206848;         // 139264 (fc1 raw)
    float* tbuf   = ws + 346112;         // 139264 (gelu out)
    float* ln1buf = ws + 485376;         // 34816
    float* ln2buf = ws + 520192;         // 34816
    float* Pg     = ws + 555008;         // 139264 (k-split planes)

    k0_init<<<136, 256, 0, stream>>>(x, bias, cls, ss, altx);
    // ss[1:17] += altx @ weight.T  (2 planes [16][2048], CH=4, NT)
    gemvP<16, 4, true><<<dim3(512, 2), 256, 0, stream>>>(
        weight, altx, Pg, 2048, 2048);
    redln<<<17, 256, 0, stream>>>(Pg, 2, 1, 32768, nullptr, ss, ln1_g, ln1_b, ln1buf);

    for (int k = 0; k < 4; ++k) {
        // qkv = Wqkv[k] @ ln1buf  (direct, L=6144, CH=8, NT: read-once)
        gemvP<17, 8, true><<<dim3(1536, 1), 256, 0, stream>>>(
            Wqkv + (size_t)k * 12582912, ln1buf, qkv, 6144, 2048);
        attn_kernel<<<16, 64, 0, stream>>>(qkv, imv);
        // Pg = imv @ Wo[k].T  (2 planes [17][2048], CH=4, NT: read-once)
        gemvP<17, 4, true><<<dim3(512, 2), 256, 0, stream>>>(
            Wo + (size_t)k * 4194304, imv, Pg, 2048, 2048);
        redln<<<17, 256, 0, stream>>>(Pg, 2, 0, 34816, nullptr, ss, ln2_g, ln2_b, ln2buf);
        // Pf = fc1_w @ ln2buf  (direct raw, L=8192, CH=8, temporal: re-read 4x)
        gemvP<17, 8, false><<<dim3(2048, 1), 256, 0, stream>>>(
            fc1_w, ln2buf, Pf, 8192, 2048);
        red_gelu<<<544, 256, 0, stream>>>(Pf, fc1_b, tbuf);
        // Pg = fc2_w @ tbuf  (2 planes [17][2048], K=8192, CH=16, temporal)
        gemvP<17, 16, false><<<dim3(512, 2), 256, 0, stream>>>(
            fc2_w, tbuf, Pg, 2048, 8192);
        if (k < 3)
            redln<<<17, 256, 0, stream>>>(Pg, 2, 0, 34816, fc2_b, ss, ln1_g, ln1_b, ln1buf);
        else
            redln<<<17, 256, 0, stream>>>(Pg, 2, 0, 34816, fc2_b, ss, ln3_g, ln3_b, out);
    }
}